// Round 8
// baseline (4532.543 us; speedup 1.0000x reference)
//
#include <hip/hip_runtime.h>
#include <hip/hip_bf16.h>

using bf16x8 = __attribute__((ext_vector_type(8))) __bf16;
using short8 = __attribute__((ext_vector_type(8))) short;
using f32x4  = __attribute__((ext_vector_type(4))) float;
using f4     = __attribute__((ext_vector_type(4))) float;
using i32x4  = __attribute__((ext_vector_type(4))) int;

constexpr int NB = 128;    // batch
constexpr int NT = 256;    // time
constexpr int NH = 1024;   // hidden
constexpr int NE = 256;    // embed
constexpr int NV = 256;    // vocab

constexpr int WHH_BYTES = 48 * 2048;    // 98304: 48 rows x 1024 bf16
constexpr int GH_FLOATS = 20 * 256;     // 18 hh-partial tiles + 2 i_n tiles
constexpr int NBLK = 256;

// ---- cache-bypass (coherence-point) memory ops: no bulk wbl2/inv needed ----
__device__ __forceinline__ void ldg_sc(i32x4& d, const void* p) {
  asm volatile("global_load_dwordx4 %0, %1, off sc0 sc1" : "=v"(d) : "v"(p));
}
__device__ __forceinline__ void stg_sc_u16(void* p, unsigned int v) {
  asm volatile("global_store_short %0, %1, off sc0 sc1" :: "v"(p), "v"(v) : "memory");
}
__device__ __forceinline__ void vm0_fence() {
  asm volatile("s_waitcnt vmcnt(0)" ::: "memory");
}
__device__ __forceinline__ void use_dep(i32x4& d) {
  asm volatile("" : "+v"(d));
}

// 8 contiguous f32 -> bf16x8 (RNE)
__device__ __forceinline__ bf16x8 cvt8(const float* p) {
  short8 r;
  #pragma unroll
  for (int j = 0; j < 8; ++j)
    r[j] = (short)__bfloat16_as_ushort(__float2bfloat16(p[j]));
  return __builtin_bit_cast(bf16x8, r);
}

__global__ __launch_bounds__(256) void embcvt_kernel(const float* __restrict__ e,
                                                     __hip_bfloat16* __restrict__ o) {
  int i = blockIdx.x * 256 + threadIdx.x;
  o[i] = __float2bfloat16(e[i]);
}

// 256 WGs x 384 threads. WG owns h'[rb*32:+32, c0:+16]. Wave wv=(mt,ks):
// mt = 16-row m-tile, ks = K-slice 0..2 (doubles as input-GEMM gate).
// Packed per-group flags (64 x 4B = 4 lines). Per-wave two-phase ballot
// polling: wait producers 0..31 -> issue first-half A sc-loads -> input
// GEMM part 2 -> wait 32..63 -> issue rest. Publish = direct 2B sc-stores
// from the gates loop. Input partials folded into hh partials for r,z.
template<int LAYER>
__global__ __launch_bounds__(384, 2) void gru_kernel(
    const int* __restrict__ x,
    const __hip_bfloat16* __restrict__ embb,
    const float* __restrict__ Wih,
    const float* __restrict__ Whh,
    const float* __restrict__ bih,
    const float* __restrict__ bhh,
    const float* __restrict__ h0,
    const __hip_bfloat16* __restrict__ yin,
    __hip_bfloat16* __restrict__ yout,
    __hip_bfloat16* __restrict__ hbuf,        // [2][128][1024]
    float* __restrict__ hout,
    unsigned int* __restrict__ flags)         // [4][64] packed uints
{
  extern __shared__ char smem[];
  char*  sWhh  = smem;
  float* sGh   = (float*)(smem + WHH_BYTES);
  float* sBias = sGh + GH_FLOATS;

  const int tid  = threadIdx.x;
  const int lane = tid & 63;
  const int wv   = tid >> 6;
  const int mt   = wv & 1;
  const int ks   = wv >> 1;                   // K-slice / input gate, 0..2
  const int b    = blockIdx.x;
  const int rb   = (b >> 1) & 3;
  const int cidx = (b & 1) * 32 + (b >> 3);
  const int r0   = rb * 32;
  const int c0   = cidx * 16;
  unsigned int* pf = flags + rb * 64;         // packed: 64 x 4B
  const int slot = cidx;
  const int l16  = lane & 15;
  const int lk8  = (lane >> 4) * 8;

  // ---- stage W_hh slice swizzled (rows gate-major: gr>>4 = gate) ----
  for (int it = 0; it < 16; ++it) {
    int idx = it * 384 + tid;
    int gr = idx >> 7, kc = idx & 127;
    int grow = (gr >> 4) * NH + c0 + (gr & 15);
    short8 v = __builtin_bit_cast(short8, cvt8(Whh + grow * NH + kc * 8));
    *(short8*)(sWhh + ((gr * 2048 + kc * 16) ^ ((gr & 7) << 4))) = v;
  }
  if (tid < 16)       sBias[tid] = bih[c0 + tid] + bhh[c0 + tid];
  else if (tid < 32)  { int c = NH + c0 + tid - 16;   sBias[tid] = bih[c] + bhh[c]; }
  else if (tid < 48)  { int c = 2*NH + c0 + tid - 32; sBias[tid] = bih[c]; }
  else if (tid < 64)  { int c = 2*NH + c0 + tid - 48; sBias[tid] = bhh[c]; }

  // ---- W_ih fully in VGPR fragments (wave's input gate = ks) ----
  constexpr int NFRAG = (LAYER == 0) ? 8 : 32;
  constexpr int KIN   = (LAYER == 0) ? NE : NH;
  bf16x8 wreg[NFRAG];
  #pragma unroll
  for (int kf = 0; kf < NFRAG; ++kf) {
    int grow = ks * NH + c0 + l16;
    wreg[kf] = cvt8(Wih + grow * KIN + kf * 32 + lk8);
  }

  // ---- init h0 -> regs + direct sc publish of hbuf[0] + flag=1 ----
  float hown[2] = {0.f, 0.f};
  #pragma unroll
  for (int ei = 0; ei < 2; ++ei) {
    int e = tid + ei * 384;
    if (e < 512) {
      float hv = h0[(r0 + (e >> 4)) * NH + c0 + (e & 15)];
      hown[ei] = hv;
      unsigned int bits = (unsigned int)__bfloat16_as_ushort(__float2bfloat16(hv));
      stg_sc_u16(hbuf + (r0 + (e >> 4)) * NH + c0 + (e & 15), bits);
    }
  }
  vm0_fence();
  __syncthreads();
  if (tid == 0)
    __hip_atomic_store(pf + slot, 1u, __ATOMIC_RELAXED,
                       __HIP_MEMORY_SCOPE_AGENT);

  // ---- time loop ----
  for (int t = 0; t < NT; ++t) {
    const __hip_bfloat16* rbuf = hbuf + (t & 1) * (NB * NH);
    __hip_bfloat16* wbuf = hbuf + ((t + 1) & 1) * (NB * NH);
    const int arow = r0 + mt * 16 + l16;
    const int bxor = (l16 & 7) << 4;
    float* abase = sGh + (lane >> 4) * 64 + l16;
    const unsigned int ep = (unsigned int)(t + 1);

    // ---- 1a. input GEMM part 1 (cached, overlaps producers' publish) ----
    constexpr int P1 = (LAYER == 0) ? 4 : 20;
    f32x4 ai = {0.f, 0.f, 0.f, 0.f};
    const __hip_bfloat16* xptr;
    if constexpr (LAYER == 0) {
      int xid = x[arow * NT + t];
      xptr = embb + xid * NE + lk8;
    } else {
      xptr = yin + (arow * NT + t) * NH + lk8;
    }
    #pragma unroll
    for (int kk = 0; kk < P1; ++kk) {
      bf16x8 a = __builtin_bit_cast(bf16x8, *(const short8*)(xptr + kk * 32));
      ai = __builtin_amdgcn_mfma_f32_16x16x32_bf16(a, wreg[kk], ai, 0, 0, 0);
    }

    // ---- 2a. per-wave phase-1 wait: producers 0..31 (cols < 512) ----
    {
      unsigned int fv = __hip_atomic_load(pf + lane, __ATOMIC_RELAXED,
                                          __HIP_MEMORY_SCOPE_AGENT);
      while ((__ballot(fv >= ep) & 0xFFFFFFFFull) != 0xFFFFFFFFull) {
        __builtin_amdgcn_s_sleep(1);
        fv = __hip_atomic_load(pf + lane, __ATOMIC_RELAXED,
                               __HIP_MEMORY_SCOPE_AGENT);
      }
    }

    // ---- 3a. issue first-half A sc-loads (chunks kk < 16) ----
    const int nk = (ks < 2) ? 11 : 10;
    const int n1 = (15 - ks) / 3 + 1;         // ks0:6 ks1:5 ks2:5
    const __hip_bfloat16* aptr = rbuf + arow * NH + lk8;
    i32x4 fr[11];
    #pragma unroll
    for (int i = 0; i < 11; ++i)
      if (i < n1) ldg_sc(fr[i], aptr + (ks + 3 * i) * 32);

    // ---- 1b. input GEMM part 2 (overlaps loads + phase-2 publish) ----
    #pragma unroll
    for (int kk = P1; kk < NFRAG; ++kk) {
      bf16x8 a = __builtin_bit_cast(bf16x8, *(const short8*)(xptr + kk * 32));
      ai = __builtin_amdgcn_mfma_f32_16x16x32_bf16(a, wreg[kk], ai, 0, 0, 0);
    }

    // ---- 2b. phase-2 wait: producers 32..63 ----
    {
      unsigned int fv = __hip_atomic_load(pf + lane, __ATOMIC_RELAXED,
                                          __HIP_MEMORY_SCOPE_AGENT);
      while (__ballot(fv >= ep) != 0xFFFFFFFFFFFFFFFFull) {
        __builtin_amdgcn_s_sleep(1);
        fv = __hip_atomic_load(pf + lane, __ATOMIC_RELAXED,
                               __HIP_MEMORY_SCOPE_AGENT);
      }
    }

    // ---- 3b. issue remaining A sc-loads ----
    #pragma unroll
    for (int i = 0; i < 11; ++i)
      if (i >= n1 && i < nk) ldg_sc(fr[i], aptr + (ks + 3 * i) * 32);

    vm0_fence();
    #pragma unroll
    for (int i = 0; i < 11; ++i)
      if (i < nk) use_dep(fr[i]);

    // ---- 4. W_hh MFMAs: A from regs, all 3 gates per chunk ----
    {
      f32x4 ah0 = {0.f,0.f,0.f,0.f}, ah1 = {0.f,0.f,0.f,0.f}, ah2 = {0.f,0.f,0.f,0.f};
      const int bb0 = (l16)      * 2048 + lk8 * 2;
      const int bb1 = (16 + l16) * 2048 + lk8 * 2;
      const int bb2 = (32 + l16) * 2048 + lk8 * 2;
      #pragma unroll
      for (int i = 0; i < 11; ++i) {
        if (i < nk) {
          int kk = ks + 3 * i;
          bf16x8 a = __builtin_bit_cast(bf16x8, fr[i]);
          bf16x8 b0 = __builtin_bit_cast(bf16x8,
              *(const short8*)(sWhh + ((bb0 + kk * 64) ^ bxor)));
          ah0 = __builtin_amdgcn_mfma_f32_16x16x32_bf16(a, b0, ah0, 0, 0, 0);
          bf16x8 b1 = __builtin_bit_cast(bf16x8,
              *(const short8*)(sWhh + ((bb1 + kk * 64) ^ bxor)));
          ah1 = __builtin_amdgcn_mfma_f32_16x16x32_bf16(a, b1, ah1, 0, 0, 0);
          bf16x8 b2 = __builtin_bit_cast(bf16x8,
              *(const short8*)(sWhh + ((bb2 + kk * 64) ^ bxor)));
          ah2 = __builtin_amdgcn_mfma_f32_16x16x32_bf16(a, b2, ah2, 0, 0, 0);
        }
      }
      // fold input partial: r,z sum linearly; i_n must stay separate
      if (ks == 0)      ah0 += ai;
      else if (ks == 1) ah1 += ai;
      // partials -> disjoint tiles [ks*6 + mt*3 + g]
      float* p0 = abase + (ks * 6 + mt * 3 + 0) * 256;
      float* p1 = abase + (ks * 6 + mt * 3 + 1) * 256;
      float* p2 = abase + (ks * 6 + mt * 3 + 2) * 256;
      p0[0] = ah0[0]; p0[16] = ah0[1]; p0[32] = ah0[2]; p0[48] = ah0[3];
      p1[0] = ah1[0]; p1[16] = ah1[1]; p1[32] = ah1[2]; p1[48] = ah1[3];
      p2[0] = ah2[0]; p2[16] = ah2[1]; p2[32] = ah2[2]; p2[48] = ah2[3];
      if (ks == 2) {
        float* pi = abase + (18 + mt) * 256;
        pi[0] = ai[0]; pi[16] = ai[1]; pi[32] = ai[2]; pi[48] = ai[3];
      }
    }
    __syncthreads();

    // ---- 5. gates: sum ks-partials; direct sc publish of h' ----
    #pragma unroll
    for (int ei = 0; ei < 2; ++ei) {
      int e = tid + ei * 384;
      if (e < 512) {
        int lrow = e >> 4, lcol = e & 15;
        int m2 = lrow >> 4, off = (lrow & 15) * 16 + lcol;
        float ghr = sGh[(0 + m2*3 + 0) * 256 + off]
                  + sGh[(6 + m2*3 + 0) * 256 + off]
                  + sGh[(12 + m2*3 + 0) * 256 + off];
        float ghz = sGh[(0 + m2*3 + 1) * 256 + off]
                  + sGh[(6 + m2*3 + 1) * 256 + off]
                  + sGh[(12 + m2*3 + 1) * 256 + off];
        float ghn = sGh[(0 + m2*3 + 2) * 256 + off]
                  + sGh[(6 + m2*3 + 2) * 256 + off]
                  + sGh[(12 + m2*3 + 2) * 256 + off];
        float gin = sGh[(18 + m2) * 256 + off];
        float r = 1.f / (1.f + __expf(-(ghr + sBias[lcol])));
        float z = 1.f / (1.f + __expf(-(ghz + sBias[16 + lcol])));
        float npre = (gin + sBias[32 + lcol]) + r * (ghn + sBias[48 + lcol]);
        float n = 2.f / (1.f + __expf(-2.f * npre)) - 1.f;   // tanh, inf-safe
        float hn = (1.f - z) * n + z * hown[ei];
        hown[ei] = hn;
        __hip_bfloat16 hb = __float2bfloat16(hn);
        unsigned int bits = (unsigned int)__bfloat16_as_ushort(hb);
        stg_sc_u16(wbuf + (r0 + lrow) * NH + c0 + lcol, bits);
        if constexpr (LAYER == 0)
          yout[((r0 + lrow) * NT + t) * NH + c0 + lcol] = hb;
      }
    }

    // ---- 6. ack + flag epoch t+2 ----
    vm0_fence();
    __syncthreads();
    if (tid == 0)
      __hip_atomic_store(pf + slot, (unsigned int)(t + 2),
                         __ATOMIC_RELAXED, __HIP_MEMORY_SCOPE_AGENT);
  }

  #pragma unroll
  for (int ei = 0; ei < 2; ++ei) {
    int e = tid + ei * 384;
    if (e < 512) {
      int lrow = e >> 4, lcol = e & 15;
      hout[(r0 + lrow) * NH + c0 + lcol] = hown[ei];
    }
  }
}

__global__ __launch_bounds__(256) void logits_kernel(
    const __hip_bfloat16* __restrict__ h1,
    const float* __restrict__ fcW,
    const float* __restrict__ fcb,
    float* __restrict__ out)
{
  __shared__ float hrow[NH];
  int b = blockIdx.x, v = threadIdx.x;
  if (v < 128) {
    i32x4 hv;
    ldg_sc(hv, h1 + b * NH + v * 8);
    vm0_fence();
    use_dep(hv);
    short8 s = __builtin_bit_cast(short8, hv);
    #pragma unroll
    for (int j = 0; j < 8; ++j) {
      union { unsigned int i; float f; } c;
      c.i = ((unsigned int)(unsigned short)s[j]) << 16;
      hrow[v * 8 + j] = c.f;
    }
  }
  __syncthreads();
  float acc = fcb[v];
  for (int k = 0; k < NH; k += 4) {
    f4 wv = *(const f4*)(fcW + v * NH + k);
    #pragma unroll
    for (int j = 0; j < 4; ++j) acc += wv[j] * hrow[k + j];
  }
  out[b * NV + v] = acc;
}

extern "C" void kernel_launch(void* const* d_in, const int* in_sizes, int n_in,
                              void* d_out, int out_size, void* d_ws, size_t ws_size,
                              hipStream_t stream) {
  const int*   x    = (const int*)d_in[0];
  const float* h0   = (const float*)d_in[1];
  const float* emb  = (const float*)d_in[2];
  const float* Wih0 = (const float*)d_in[3];
  const float* Whh0 = (const float*)d_in[4];
  const float* bih0 = (const float*)d_in[5];
  const float* bhh0 = (const float*)d_in[6];
  const float* Wih1 = (const float*)d_in[7];
  const float* Whh1 = (const float*)d_in[8];
  const float* bih1 = (const float*)d_in[9];
  const float* bhh1 = (const float*)d_in[10];
  const float* fcW  = (const float*)d_in[11];
  const float* fcb  = (const float*)d_in[12];
  float* out = (float*)d_out;

  char* ws = (char*)d_ws;
  size_t off = 0;
  __hip_bfloat16* y0   = (__hip_bfloat16*)ws;            off += (size_t)NB * NT * NH * 2;
  __hip_bfloat16* hbuf = (__hip_bfloat16*)(ws + off);    off += (size_t)2 * NB * NH * 2;
  __hip_bfloat16* embb = (__hip_bfloat16*)(ws + off);    off += (size_t)NV * NE * 2;
  unsigned int*  flags0 = (unsigned int*)(ws + off);     off += 4 * 64 * 4;
  unsigned int*  flags1 = (unsigned int*)(ws + off);     off += 4 * 64 * 4;

  (void)hipMemsetAsync(flags0, 0, 2 * 4 * 64 * 4, stream);
  embcvt_kernel<<<dim3(NV * NE / 256), dim3(256), 0, stream>>>(emb, embb);

  constexpr int lds = WHH_BYTES + GH_FLOATS * 4 + 64 * 4;  // 119040
  (void)hipFuncSetAttribute(reinterpret_cast<const void*>(gru_kernel<0>),
                            hipFuncAttributeMaxDynamicSharedMemorySize, lds);
  (void)hipFuncSetAttribute(reinterpret_cast<const void*>(gru_kernel<1>),
                            hipFuncAttributeMaxDynamicSharedMemorySize, lds);

  gru_kernel<0><<<dim3(NBLK), dim3(384), lds, stream>>>(
      x, embb, Wih0, Whh0, bih0, bhh0, h0, y0, y0, hbuf, out + 32768, flags0);
  gru_kernel<1><<<dim3(NBLK), dim3(384), lds, stream>>>(
      x, embb, Wih1, Whh1, bih1, bhh1, h0 + NB * NH, y0, y0, hbuf,
      out + 32768 + NB * NH, flags1);
  logits_kernel<<<dim3(NB), dim3(256), 0, stream>>>(hbuf, fcW, fcb, out);
}